// Round 1
// baseline (3556.298 us; speedup 1.0000x reference)
//
#include <hip/hip_runtime.h>

// LSTM char-RNN forward: batch=1024, T=512, UNITS=256, NUM_CHARS=128.
// Per-batch-row recurrence is independent -> 256 persistent blocks x 4 rows,
// no inter-block sync. Wh streamed from L2 as fp16 (gate-interleaved),
// fp32 state/accum. v_dot2_f32_f16 when available.

#define BATCH   1024
#define TSTEPS  512
#define UNITS   256
#define NCHAR   128
#define G4      1024   // 4*UNITS

typedef _Float16 f16x2 __attribute__((ext_vector_type(2)));

union H2U { unsigned int u; f16x2 h; };
union U4  { uint4 v; unsigned int a[4]; };

#if __has_builtin(__builtin_amdgcn_fdot2)
#define HAS_FDOT2 1
#endif

__device__ __forceinline__ float dot2_acc(unsigned int w, unsigned int h, float acc) {
  H2U a; a.u = w; H2U b; b.u = h;
#ifdef HAS_FDOT2
  return __builtin_amdgcn_fdot2(a.h, b.h, acc, false);
#else
  return acc + (float)a.h.x * (float)b.h.x + (float)a.h.y * (float)b.h.y;
#endif
}

__device__ __forceinline__ float fast_rcp(float x) {
#if __has_builtin(__builtin_amdgcn_rcpf)
  return __builtin_amdgcn_rcpf(x);
#else
  return 1.0f / x;
#endif
}

__device__ __forceinline__ float sigm(float x)  { return fast_rcp(1.0f + __expf(-x)); }
__device__ __forceinline__ float tanhx(float x) { return 2.0f * fast_rcp(1.0f + __expf(-2.0f * x)) - 1.0f; }

// ---- Prep: Wh [256,1024] fp32 -> Whp [128 k2][256 u] uint4 of half2 pairs
// Whp[k2*256+u].a[g] = half2( Wh[2k2][g*256+u], Wh[2k2+1][g*256+u] )
__global__ void prep_wh(const float* __restrict__ Wh, uint4* __restrict__ Whp) {
  int idx = blockIdx.x * blockDim.x + threadIdx.x;   // 0..32767
  int u  = idx & (UNITS - 1);
  int k2 = idx >> 8;
  const float* r0 = Wh + (2 * k2) * G4;
  const float* r1 = Wh + (2 * k2 + 1) * G4;
  U4 o;
#pragma unroll
  for (int g = 0; g < 4; ++g) {
    H2U v;
    v.h = f16x2{(_Float16)r0[g * UNITS + u], (_Float16)r1[g * UNITS + u]};
    o.a[g] = v.u;
  }
  Whp[idx] = o.v;
}

// ---- Prep: Wxbg [128 ch][256 u] float4 = Wx[ch][g*256+u] + b[g*256+u]
__global__ void prep_wx(const float* __restrict__ Wx, const float* __restrict__ bias,
                        float4* __restrict__ Wxbg) {
  int idx = blockIdx.x * blockDim.x + threadIdx.x;   // 0..32767
  int u  = idx & (UNITS - 1);
  int ch = idx >> 8;
  const float* r = Wx + ch * G4;
  float4 o;
  o.x = r[0 * UNITS + u] + bias[0 * UNITS + u];
  o.y = r[1 * UNITS + u] + bias[1 * UNITS + u];
  o.z = r[2 * UNITS + u] + bias[2 * UNITS + u];
  o.w = r[3 * UNITS + u] + bias[3 * UNITS + u];
  Wxbg[idx] = o;
}

// ---- Main persistent LSTM kernel: 256 blocks x 512 threads, 4 rows/block.
// Lower 256 threads: unit u, k2 in [0,64); upper: same unit u, k2 in [64,128).
__global__ __launch_bounds__(512, 2) void lstm_main(
    const int* __restrict__ inp, const uint4* __restrict__ Whp,
    const float4* __restrict__ Wxbg, const float* __restrict__ Wd,
    const float* __restrict__ bd, float* __restrict__ out) {
  __shared__ __align__(16) unsigned int h1t[128 * 4];  // [k2][r] half2(h[2k2],h[2k2+1])
  __shared__ float4 red[256][4];                       // upper-half partial accs
  __shared__ float  hf[4][UNITS];                      // final h fp32
  __shared__ float  sm[4][NCHAR];                      // logits
  __shared__ float  mrow[4], srow[4];

  const int tid   = threadIdx.x;
  const int u     = tid & 255;
  const int kh    = tid >> 8;          // 0=lower, 1=upper K half
  const int kbase = kh * 64;
  const int row0  = blockIdx.x * 4;

  float c[4] = {0.f, 0.f, 0.f, 0.f};

  if (kh == 0) {
    _Float16* hh = (_Float16*)h1t;
#pragma unroll
    for (int r = 0; r < 4; ++r) hh[(u >> 1) * 8 + 2 * r + (u & 1)] = (_Float16)0.f;
  }
  __syncthreads();

  const uint4* wp = Whp + kbase * 256 + u;
  const uint4* hp = (const uint4*)&h1t[kbase * 4];

  for (int t = 0; t < TSTEPS; ++t) {
    float a[4][4];
#pragma unroll
    for (int r = 0; r < 4; ++r) { a[r][0] = 0.f; a[r][1] = 0.f; a[r][2] = 0.f; a[r][3] = 0.f; }

#pragma unroll 4
    for (int k2 = 0; k2 < 64; ++k2) {
      U4 w;  w.v  = wp[k2 * 256];
      U4 hv; hv.v = hp[k2];
#pragma unroll
      for (int r = 0; r < 4; ++r)
#pragma unroll
        for (int g = 0; g < 4; ++g)
          a[r][g] = dot2_acc(w.a[g], hv.a[r], a[r][g]);
    }

    if (kh == 1) {
#pragma unroll
      for (int r = 0; r < 4; ++r)
        red[u][r] = make_float4(a[r][0], a[r][1], a[r][2], a[r][3]);
    }
    __syncthreads();  // upper partials visible; all threads done reading h1t

    if (kh == 0) {
      _Float16* hh = (_Float16*)h1t;
#pragma unroll
      for (int r = 0; r < 4; ++r) {
        float4 v  = red[u][r];
        int   ch  = inp[(row0 + r) * TSTEPS + t];
        float4 xb = Wxbg[ch * UNITS + u];
        float zi = a[r][0] + v.x + xb.x;
        float zf = a[r][1] + v.y + xb.y;
        float zg = a[r][2] + v.z + xb.z;
        float zo = a[r][3] + v.w + xb.w;
        float ig = sigm(zi);
        float fg = sigm(zf);
        float gg = tanhx(zg);
        float og = sigm(zo);
        float cn = fg * c[r] + ig * gg;
        c[r] = cn;
        float hn = og * tanhx(cn);
        hh[(u >> 1) * 8 + 2 * r + (u & 1)] = (_Float16)hn;
        if (t == TSTEPS - 1) hf[r][u] = hn;
      }
    }
    __syncthreads();  // h1t(t+1) ready
  }

  // ---- Epilogue: logits = hf @ Wd + bd, then softmax per row.
  if (tid < NCHAR) {
    const int j = tid;
    float lg0 = bd[j], lg1 = bd[j], lg2 = bd[j], lg3 = bd[j];
    for (int uu = 0; uu < UNITS; ++uu) {
      float w = Wd[uu * NCHAR + j];
      lg0 += hf[0][uu] * w;
      lg1 += hf[1][uu] * w;
      lg2 += hf[2][uu] * w;
      lg3 += hf[3][uu] * w;
    }
    sm[0][j] = lg0; sm[1][j] = lg1; sm[2][j] = lg2; sm[3][j] = lg3;
  }
  __syncthreads();
  if (tid < 4) {
    const int r = tid;
    float m = -1e30f;
    for (int j = 0; j < NCHAR; ++j) m = fmaxf(m, sm[r][j]);
    float s = 0.f;
    for (int j = 0; j < NCHAR; ++j) s += __expf(sm[r][j] - m);
    mrow[r] = m;
    srow[r] = fast_rcp(s);
  }
  __syncthreads();
  if (tid < NCHAR) {
    const int j = tid;
#pragma unroll
    for (int r = 0; r < 4; ++r)
      out[(row0 + r) * NCHAR + j] = __expf(sm[r][j] - mrow[r]) * srow[r];
  }
}

extern "C" void kernel_launch(void* const* d_in, const int* in_sizes, int n_in,
                              void* d_out, int out_size, void* d_ws, size_t ws_size,
                              hipStream_t stream) {
  const int*   inp = (const int*)d_in[0];
  const float* Wx  = (const float*)d_in[1];
  const float* Wh  = (const float*)d_in[2];
  const float* bia = (const float*)d_in[3];
  const float* Wd  = (const float*)d_in[4];
  const float* bd  = (const float*)d_in[5];

  uint4*  Whp  = (uint4*)d_ws;                              // 512 KB
  float4* Wxbg = (float4*)((char*)d_ws + (512 << 10));      // 512 KB

  prep_wh<<<128, 256, 0, stream>>>(Wh, Whp);
  prep_wx<<<128, 256, 0, stream>>>(Wx, bia, Wxbg);
  lstm_main<<<256, 512, 0, stream>>>(inp, Whp, Wxbg, Wd, bd, (float*)d_out);
}

// Round 2
// 2797.024 us; speedup vs baseline: 1.2715x; 1.2715x over previous
//
#include <hip/hip_runtime.h>

// LSTM char-RNN forward: batch=1024, T=512, UNITS=256, NUM_CHARS=128.
// R2: Wh made on-chip resident. Per K-half (64 k2-slices): 40 slices in
// VGPRs (160 regs/thread), 17 in LDS (136 KB), 7 streamed from L2
// (56 KB/step/CU, prefetched at step top). Same accumulation order as R1
// -> identical numerics (absmax 6.1e-5).

#define BATCH   1024
#define TSTEPS  512
#define UNITS   256
#define NCHAR   128
#define G4      1024   // 4*UNITS

#define NREG 40
#define NLDS 17
#define NL2  7         // NREG+NLDS+NL2 == 64

typedef _Float16 f16x2 __attribute__((ext_vector_type(2)));

union H2U { unsigned int u; f16x2 h; };
union U4  { uint4 v; unsigned int a[4]; };

#if __has_builtin(__builtin_amdgcn_fdot2)
#define HAS_FDOT2 1
#endif

__device__ __forceinline__ float dot2_acc(unsigned int w, unsigned int h, float acc) {
  H2U a; a.u = w; H2U b; b.u = h;
#ifdef HAS_FDOT2
  return __builtin_amdgcn_fdot2(a.h, b.h, acc, false);
#else
  return acc + (float)a.h.x * (float)b.h.x + (float)a.h.y * (float)b.h.y;
#endif
}

__device__ __forceinline__ float fast_rcp(float x) {
#if __has_builtin(__builtin_amdgcn_rcpf)
  return __builtin_amdgcn_rcpf(x);
#else
  return 1.0f / x;
#endif
}

__device__ __forceinline__ float sigm(float x)  { return fast_rcp(1.0f + __expf(-x)); }
__device__ __forceinline__ float tanhx(float x) { return 2.0f * fast_rcp(1.0f + __expf(-2.0f * x)) - 1.0f; }

// ---- Prep: Wh [256,1024] fp32 -> Whp [128 k2][256 u] uint4 of half2 pairs
__global__ void prep_wh(const float* __restrict__ Wh, uint4* __restrict__ Whp) {
  int idx = blockIdx.x * blockDim.x + threadIdx.x;   // 0..32767
  int u  = idx & (UNITS - 1);
  int k2 = idx >> 8;
  const float* r0 = Wh + (2 * k2) * G4;
  const float* r1 = Wh + (2 * k2 + 1) * G4;
  U4 o;
#pragma unroll
  for (int g = 0; g < 4; ++g) {
    H2U v;
    v.h = f16x2{(_Float16)r0[g * UNITS + u], (_Float16)r1[g * UNITS + u]};
    o.a[g] = v.u;
  }
  Whp[idx] = o.v;
}

// ---- Prep: Wxbg [128 ch][256 u] float4 = Wx[ch][g*256+u] + b[g*256+u]
__global__ void prep_wx(const float* __restrict__ Wx, const float* __restrict__ bias,
                        float4* __restrict__ Wxbg) {
  int idx = blockIdx.x * blockDim.x + threadIdx.x;
  int u  = idx & (UNITS - 1);
  int ch = idx >> 8;
  const float* r = Wx + ch * G4;
  float4 o;
  o.x = r[0 * UNITS + u] + bias[0 * UNITS + u];
  o.y = r[1 * UNITS + u] + bias[1 * UNITS + u];
  o.z = r[2 * UNITS + u] + bias[2 * UNITS + u];
  o.w = r[3 * UNITS + u] + bias[3 * UNITS + u];
  Wxbg[idx] = o;
}

// ---- Main persistent LSTM kernel: 256 blocks x 512 threads, 4 rows/block.
__global__ __launch_bounds__(512, 2) void lstm_main(
    const int* __restrict__ inp, const uint4* __restrict__ Whp,
    const float4* __restrict__ Wxbg, const float* __restrict__ Wd,
    const float* __restrict__ bd, float* __restrict__ out) {
  __shared__ __align__(16) uint4 wlds[2 * NLDS * 256];   // 139264 B weight cache
  __shared__ __align__(16) unsigned int h1t[128 * 4];    // 2048 B: [k2][r] half2
  __shared__ float4 red[256][4];                         // 16384 B upper partials
  __shared__ float  hf[4][UNITS];                        // 4096 B final h fp32
  // total 161,792 B; epilogue sm/mrow/srow alias red (dead after last barrier)

  const int tid   = threadIdx.x;
  const int u     = tid & 255;
  const int kh    = tid >> 8;          // 0=lower, 1=upper K half
  const int row0  = blockIdx.x * 4;

  float c[4] = {0.f, 0.f, 0.f, 0.f};

  const uint4* wgrp = Whp + (kh * 64) * 256 + u;

  // ---- Preload 40 weight slices into registers (coalesced across u)
  U4 wr[NREG];
#pragma unroll
  for (int j = 0; j < NREG; ++j) wr[j].v = wgrp[j * 256];

  // ---- Fill LDS weight cache (17 slices per group)
  uint4* wl = &wlds[kh * NLDS * 256];
#pragma unroll
  for (int s = 0; s < NLDS; ++s) wl[s * 256 + u] = wgrp[(NREG + s) * 256];

  // ---- init h = 0
  if (kh == 0) {
    _Float16* hh = (_Float16*)h1t;
#pragma unroll
    for (int r = 0; r < 4; ++r) hh[(u >> 1) * 8 + 2 * r + (u & 1)] = (_Float16)0.f;
  }
  __syncthreads();

  const uint4* hp   = (const uint4*)&h1t[kh * 64 * 4];
  const uint4* wpL2 = wgrp + (NREG + NLDS) * 256;

  for (int t = 0; t < TSTEPS; ++t) {
    // prefetch the 7 L2-resident slices; hidden under the register compute
    U4 w2[NL2];
#pragma unroll
    for (int j = 0; j < NL2; ++j) w2[j].v = wpL2[j * 256];

    float a[4][4];
#pragma unroll
    for (int r = 0; r < 4; ++r) { a[r][0] = 0.f; a[r][1] = 0.f; a[r][2] = 0.f; a[r][3] = 0.f; }

    // 1) register-resident slices (j = 0..39)
#pragma unroll
    for (int j = 0; j < NREG; ++j) {
      U4 hv; hv.v = hp[j];
#pragma unroll
      for (int r = 0; r < 4; ++r)
#pragma unroll
        for (int g = 0; g < 4; ++g)
          a[r][g] = dot2_acc(wr[j].a[g], hv.a[r], a[r][g]);
    }
    // 2) LDS-resident slices (j = 40..56)
#pragma unroll
    for (int s = 0; s < NLDS; ++s) {
      U4 hv; hv.v = hp[NREG + s];
      U4 w;  w.v  = wl[s * 256 + u];
#pragma unroll
      for (int r = 0; r < 4; ++r)
#pragma unroll
        for (int g = 0; g < 4; ++g)
          a[r][g] = dot2_acc(w.a[g], hv.a[r], a[r][g]);
    }
    // 3) L2-streamed slices (j = 57..63)
#pragma unroll
    for (int j = 0; j < NL2; ++j) {
      U4 hv; hv.v = hp[NREG + NLDS + j];
#pragma unroll
      for (int r = 0; r < 4; ++r)
#pragma unroll
        for (int g = 0; g < 4; ++g)
          a[r][g] = dot2_acc(w2[j].a[g], hv.a[r], a[r][g]);
    }

    if (kh == 1) {
#pragma unroll
      for (int r = 0; r < 4; ++r)
        red[u][r] = make_float4(a[r][0], a[r][1], a[r][2], a[r][3]);
    }
    __syncthreads();  // upper partials visible; all threads done reading h1t

    if (kh == 0) {
      _Float16* hh = (_Float16*)h1t;
#pragma unroll
      for (int r = 0; r < 4; ++r) {
        float4 v  = red[u][r];
        int   ch  = inp[(row0 + r) * TSTEPS + t];
        float4 xb = Wxbg[ch * UNITS + u];
        float zi = a[r][0] + v.x + xb.x;
        float zf = a[r][1] + v.y + xb.y;
        float zg = a[r][2] + v.z + xb.z;
        float zo = a[r][3] + v.w + xb.w;
        float ig = sigm(zi);
        float fg = sigm(zf);
        float gg = tanhx(zg);
        float og = sigm(zo);
        float cn = fg * c[r] + ig * gg;
        c[r] = cn;
        float hn = og * tanhx(cn);
        hh[(u >> 1) * 8 + 2 * r + (u & 1)] = (_Float16)hn;
        if (t == TSTEPS - 1) hf[r][u] = hn;
      }
    }
    __syncthreads();  // h1t(t+1) ready
  }

  // ---- Epilogue: logits = hf @ Wd + bd, softmax. sm/mrow/srow alias red
  // (red is dead after the final barrier above).
  float* sm   = (float*)red;          // [4][NCHAR]
  float* mrow = sm + 4 * NCHAR;       // [4]
  float* srow = mrow + 4;             // [4]

  if (tid < NCHAR) {
    const int j = tid;
    float lg0 = bd[j], lg1 = bd[j], lg2 = bd[j], lg3 = bd[j];
    for (int uu = 0; uu < UNITS; ++uu) {
      float w = Wd[uu * NCHAR + j];
      lg0 += hf[0][uu] * w;
      lg1 += hf[1][uu] * w;
      lg2 += hf[2][uu] * w;
      lg3 += hf[3][uu] * w;
    }
    sm[0 * NCHAR + j] = lg0; sm[1 * NCHAR + j] = lg1;
    sm[2 * NCHAR + j] = lg2; sm[3 * NCHAR + j] = lg3;
  }
  __syncthreads();
  if (tid < 4) {
    const int r = tid;
    float m = -1e30f;
    for (int j = 0; j < NCHAR; ++j) m = fmaxf(m, sm[r * NCHAR + j]);
    float s = 0.f;
    for (int j = 0; j < NCHAR; ++j) s += __expf(sm[r * NCHAR + j] - m);
    mrow[r] = m;
    srow[r] = fast_rcp(s);
  }
  __syncthreads();
  if (tid < NCHAR) {
    const int j = tid;
#pragma unroll
    for (int r = 0; r < 4; ++r)
      out[(row0 + r) * NCHAR + j] = __expf(sm[r * NCHAR + j] - mrow[r]) * srow[r];
  }
}

extern "C" void kernel_launch(void* const* d_in, const int* in_sizes, int n_in,
                              void* d_out, int out_size, void* d_ws, size_t ws_size,
                              hipStream_t stream) {
  const int*   inp = (const int*)d_in[0];
  const float* Wx  = (const float*)d_in[1];
  const float* Wh  = (const float*)d_in[2];
  const float* bia = (const float*)d_in[3];
  const float* Wd  = (const float*)d_in[4];
  const float* bd  = (const float*)d_in[5];

  uint4*  Whp  = (uint4*)d_ws;                              // 512 KB
  float4* Wxbg = (float4*)((char*)d_ws + (512 << 10));      // 512 KB

  prep_wh<<<128, 256, 0, stream>>>(Wh, Whp);
  prep_wx<<<128, 256, 0, stream>>>(Wx, bia, Wxbg);
  lstm_main<<<256, 512, 0, stream>>>(inp, Whp, Wxbg, Wd, bd, (float*)d_out);
}